// Round 10
// baseline (321.822 us; speedup 1.0000x reference)
//
#include <hip/hip_runtime.h>
#include <hip/hip_bf16.h>
#include <math.h>

// ---------------------------------------------------------------------------
// CausalSelfAttention: B=2, S=2048, D=1024, H=16, Hd=64.
// Inputs x/Wq/Wkv f32; OUTPUT IS FLOAT32 (R9 finding: bit-identical absmax
// across all implementations <=> all compute paths correct, shared bug was
// writing bf16 ushorts into an f32 d_out; magnitudes 4.421875/3.40625 match
// the half-filled/zeroed halves exactly).
// Pipeline (R5, computationally validated): [gemm_qkv] MFMA bf16 ->
// [rope_qk] Q,K (B,H,S,Hd) -> [v_transpose] Vt (B,H,Hd,S) -> [attn] flash
// causal, f32 epilogue store.
// ---------------------------------------------------------------------------

typedef short bfrag __attribute__((ext_vector_type(8)));   // 8 bf16 = 4 VGPR
typedef float f32x4 __attribute__((ext_vector_type(4)));

__device__ __forceinline__ float bf2f(ushort u) {
    union { uint i; float f; } v; v.i = ((uint)u) << 16; return v.f;
}
__device__ __forceinline__ ushort f2bf(float f) {
    union { uint i; float f; } v; v.f = f;
    uint u = v.i;
    return (ushort)((u + 0x7fffu + ((u >> 16) & 1u)) >> 16);  // RNE
}

#define MFMA16 __builtin_amdgcn_mfma_f32_16x16x32_bf16

// ---------------------------------------------------------------------------
// Kernel 1: raw[m][n] = sum_k x[m][k] * W[n][k]; m in [0,4096), n in [0,3072)
// W rows: n<1024 -> Wq[n], else Wkv[n-1024]. 128x128 tile, BK=32, 256 thr.
// ---------------------------------------------------------------------------
__global__ __launch_bounds__(256)
void gemm_qkv(const float* __restrict__ x, const float* __restrict__ wq,
              const float* __restrict__ wkv, ushort* __restrict__ raw)
{
    __shared__ ushort Ash[128][32];
    __shared__ ushort Bsh[128][32];

    const int tid  = threadIdx.x;
    const int lane = tid & 63, wv = tid >> 6;
    const int wm = wv >> 1, wn = wv & 1;
    const int quad = lane >> 4, li = lane & 15;
    const int m0 = blockIdx.x * 128, n0 = blockIdx.y * 128;

    f32x4 acc[4][4];
#pragma unroll
    for (int i = 0; i < 4; i++)
#pragma unroll
        for (int j = 0; j < 4; j++) acc[i][j] = (f32x4){0.f, 0.f, 0.f, 0.f};

    const int srow = tid >> 1;              // 0..127
    const int sc0  = (tid & 1) * 16;        // 0 or 16
    const int nglob = n0 + srow;
    const float* wrow = (nglob < 1024) ? (wq + nglob * 1024)
                                       : (wkv + (nglob - 1024) * 1024);
    const float* arow = x + (m0 + srow) * 1024;

    for (int k0 = 0; k0 < 1024; k0 += 32) {
        __syncthreads();
        {
            float va[16];
            const float* ga = arow + k0 + sc0;
            *(float4*)&va[0]  = *(const float4*)(ga + 0);
            *(float4*)&va[4]  = *(const float4*)(ga + 4);
            *(float4*)&va[8]  = *(const float4*)(ga + 8);
            *(float4*)&va[12] = *(const float4*)(ga + 12);
            ushort ta[16];
#pragma unroll
            for (int i = 0; i < 16; i++) ta[i] = f2bf(va[i]);
            *(uint4*)&Ash[srow][sc0]     = *(uint4*)&ta[0];
            *(uint4*)&Ash[srow][sc0 + 8] = *(uint4*)&ta[8];

            float vb[16];
            const float* gb = wrow + k0 + sc0;
            *(float4*)&vb[0]  = *(const float4*)(gb + 0);
            *(float4*)&vb[4]  = *(const float4*)(gb + 4);
            *(float4*)&vb[8]  = *(const float4*)(gb + 8);
            *(float4*)&vb[12] = *(const float4*)(gb + 12);
            ushort tb[16];
#pragma unroll
            for (int i = 0; i < 16; i++) tb[i] = f2bf(vb[i]);
            *(uint4*)&Bsh[srow][sc0]     = *(uint4*)&tb[0];
            *(uint4*)&Bsh[srow][sc0 + 8] = *(uint4*)&tb[8];
        }
        __syncthreads();

        bfrag af[4], bf[4];
#pragma unroll
        for (int i = 0; i < 4; i++)
            af[i] = *(const bfrag*)&Ash[wm * 64 + i * 16 + li][quad * 8];
#pragma unroll
        for (int j = 0; j < 4; j++)
            bf[j] = *(const bfrag*)&Bsh[wn * 64 + j * 16 + li][quad * 8];
#pragma unroll
        for (int i = 0; i < 4; i++)
#pragma unroll
            for (int j = 0; j < 4; j++)
                acc[i][j] = MFMA16(af[i], bf[j], acc[i][j], 0, 0, 0);
    }

    // epilogue: C/D layout col=lane&15, row=quad*4+reg  (m89-verified)
#pragma unroll
    for (int i = 0; i < 4; i++)
#pragma unroll
        for (int j = 0; j < 4; j++)
#pragma unroll
            for (int r = 0; r < 4; r++) {
                int m = m0 + wm * 64 + i * 16 + quad * 4 + r;
                int n = n0 + wn * 64 + j * 16 + li;
                raw[m * 3072 + n] = f2bf(acc[i][j][r]);
            }
}

// ---------------------------------------------------------------------------
// Kernel 2: RoPE on q,k; scatter to (B,H,S,Hd) bf16.
// raw row layout: [0,1024) = q (n=h*64+hd); [1024,3072) kv interleave:
// n = 1024 + (h*64+hd)*2 + {0=k,1=v}
// ---------------------------------------------------------------------------
__global__ __launch_bounds__(256)
void rope_qk(const ushort* __restrict__ raw, ushort* __restrict__ Qb,
             ushort* __restrict__ Kb)
{
    int t  = blockIdx.x * 256 + threadIdx.x;   // 4M threads
    int hd = t & 63;
    int h  = (t >> 6) & 15;
    int s  = (t >> 10) & 2047;
    int b  = t >> 21;
    int m  = b * 2048 + s;
    int fi = hd & 31;
    float invf = (float)exp((double)fi * -0.28782313662425574); // 1e4^(-fi/32)
    float thf  = (float)s * invf;
    const double TWO_PI = 6.283185307179586476925287;
    double th = (double)thf;
    double kq = __builtin_rint(th * (1.0 / TWO_PI));
    float r = (float)(th - kq * TWO_PI);
    float sn = sinf(r), cs = cosf(r);          // reduced: safe under fast-math

    const ushort* rp = raw + m * 3072;
    int odst = ((b * 16 + h) * 2048 + s) * 64 + hd;

    float qv = bf2f(rp[h * 64 + hd]);
    float qp = bf2f(rp[h * 64 + (hd ^ 32)]);
    float qr = (hd < 32) ? -qp : qp;            // rotate_half
    Qb[odst] = f2bf(qv * cs + qr * sn);

    float kv = bf2f(rp[1024 + (h * 64 + hd) * 2]);
    float kp = bf2f(rp[1024 + (h * 64 + (hd ^ 32)) * 2]);
    float kr = (hd < 32) ? -kp : kp;
    Kb[odst] = f2bf(kv * cs + kr * sn);
}

// ---------------------------------------------------------------------------
// Kernel 3: V -> Vt (B,H,Hd,S) bf16, 64x64 tiles via LDS.
// ---------------------------------------------------------------------------
__global__ __launch_bounds__(256)
void v_transpose(const ushort* __restrict__ raw, ushort* __restrict__ Vt)
{
    __shared__ ushort tile[64][65];
    const int bh = blockIdx.y;     // 0..31
    const int st = blockIdx.x;     // 0..31 (s-tile)
    const int b = bh >> 4, h = bh & 15;
    const int t = threadIdx.x;

    int sl = t >> 2, c0 = (t & 3) * 16;
    const ushort* rp = raw + (b * 2048 + st * 64 + sl) * 3072
                          + 1024 + (h * 64 + c0) * 2 + 1;
#pragma unroll
    for (int j = 0; j < 16; j++) tile[sl][c0 + j] = rp[2 * j];
    __syncthreads();
    int hd = t >> 2, s0 = (t & 3) * 16;
    ushort* op = Vt + (bh * 64 + hd) * 2048 + st * 64 + s0;
#pragma unroll
    for (int j = 0; j < 16; j++) op[j] = tile[s0 + j][hd];
}

// ---------------------------------------------------------------------------
// Kernel 4: causal flash attention. 1 WG (256 thr) = (b,h) x 64-row Q-tile.
// Wave w owns q rows [w*16, w*16+16). 64-wide K-tiles; online softmax.
// P goes C-layout -> LDS -> A-layout (m120 pattern). F32 output store.
// ---------------------------------------------------------------------------
__global__ __launch_bounds__(256)
void attn(const ushort* __restrict__ Qb, const ushort* __restrict__ Kb,
          const ushort* __restrict__ Vt, float* __restrict__ out)
{
    __shared__ ushort Ksh[64][72];      // [kpos][hd], +8 pad
    __shared__ ushort Vsh[64][72];      // [hd][kpos], +8 pad
    __shared__ ushort Psh[4][16][72];   // per-wave P, [qrow][kpos]

    const int tid  = threadIdx.x;
    const int lane = tid & 63, w = tid >> 6;
    const int quad = lane >> 4, li = lane & 15;
    const int qt = (int)gridDim.x - 1 - (int)blockIdx.x;   // heavy tiles first
    const int bh = blockIdx.y;
    const int b = bh >> 4, h = bh & 15;

    const int qrow = qt * 64 + w * 16 + li;
    const ushort* qp = Qb + (bh * 2048 + qrow) * 64;
    bfrag qa0 = *(const bfrag*)(qp + quad * 8);
    bfrag qa1 = *(const bfrag*)(qp + quad * 8 + 32);

    f32x4 o[4];
#pragma unroll
    for (int j = 0; j < 4; j++) o[j] = (f32x4){0.f, 0.f, 0.f, 0.f};
    float mrow[4], lrow[4];
#pragma unroll
    for (int r = 0; r < 4; r++) { mrow[r] = -3.0e38f; lrow[r] = 0.f; }

    const int srow = tid >> 2, sc0 = (tid & 3) * 16;
    const ushort* kbase = Kb + (size_t)bh * 2048 * 64;
    const ushort* vbase = Vt + (size_t)bh * 64 * 2048;
    const int qg0 = qt * 64 + w * 16 + quad * 4;

    for (int kt = 0; kt <= qt; ++kt) {
        __syncthreads();
        {
            const ushort* gk = kbase + (kt * 64 + srow) * 64 + sc0;
            *(uint4*)&Ksh[srow][sc0]     = *(const uint4*)gk;
            *(uint4*)&Ksh[srow][sc0 + 8] = *(const uint4*)(gk + 8);
            const ushort* gv = vbase + srow * 2048 + kt * 64 + sc0;
            *(uint4*)&Vsh[srow][sc0]     = *(const uint4*)gv;
            *(uint4*)&Vsh[srow][sc0 + 8] = *(const uint4*)(gv + 8);
        }
        __syncthreads();

        f32x4 sc[4];
#pragma unroll
        for (int j = 0; j < 4; j++) {
            bfrag kb0 = *(const bfrag*)&Ksh[j * 16 + li][quad * 8];
            bfrag kb1 = *(const bfrag*)&Ksh[j * 16 + li][quad * 8 + 32];
            f32x4 z = (f32x4){0.f, 0.f, 0.f, 0.f};
            z = MFMA16(qa0, kb0, z, 0, 0, 0);
            z = MFMA16(qa1, kb1, z, 0, 0, 0);
            sc[j] = z;
        }

        float mloc[4];
#pragma unroll
        for (int r = 0; r < 4; r++) mloc[r] = -3.0e38f;
#pragma unroll
        for (int j = 0; j < 4; j++) {
            int kg = kt * 64 + j * 16 + li;
#pragma unroll
            for (int r = 0; r < 4; r++) {
                float v = sc[j][r] * 0.125f;
                v = (kg <= qg0 + r) ? v : -3.0e38f;
                sc[j][r] = v;
                mloc[r] = fmaxf(mloc[r], v);
            }
        }
#pragma unroll
        for (int off = 1; off < 16; off <<= 1)
#pragma unroll
            for (int r = 0; r < 4; r++)
                mloc[r] = fmaxf(mloc[r], __shfl_xor(mloc[r], off));

        float alpha[4], mnew[4], rsum[4];
#pragma unroll
        for (int r = 0; r < 4; r++) {
            mnew[r]  = fmaxf(mrow[r], mloc[r]);
            alpha[r] = __expf(mrow[r] - mnew[r]);
            mrow[r]  = mnew[r];
            rsum[r]  = 0.f;
        }
#pragma unroll
        for (int j = 0; j < 4; j++)
#pragma unroll
            for (int r = 0; r < 4; r++) {
                float pv = __expf(sc[j][r] - mnew[r]);
                sc[j][r] = pv;
                rsum[r] += pv;
            }
#pragma unroll
        for (int off = 1; off < 16; off <<= 1)
#pragma unroll
            for (int r = 0; r < 4; r++)
                rsum[r] += __shfl_xor(rsum[r], off);
#pragma unroll
        for (int r = 0; r < 4; r++) lrow[r] = lrow[r] * alpha[r] + rsum[r];
#pragma unroll
        for (int j = 0; j < 4; j++)
#pragma unroll
            for (int r = 0; r < 4; r++) o[j][r] *= alpha[r];

#pragma unroll
        for (int j = 0; j < 4; j++)
#pragma unroll
            for (int r = 0; r < 4; r++)
                Psh[w][quad * 4 + r][j * 16 + li] = f2bf(sc[j][r]);
        asm volatile("" ::: "memory");
        __syncthreads();
        bfrag pa0 = *(const bfrag*)&Psh[w][li][quad * 8];
        bfrag pa1 = *(const bfrag*)&Psh[w][li][quad * 8 + 32];

#pragma unroll
        for (int j = 0; j < 4; j++) {
            bfrag vb0 = *(const bfrag*)&Vsh[j * 16 + li][quad * 8];
            bfrag vb1 = *(const bfrag*)&Vsh[j * 16 + li][quad * 8 + 32];
            o[j] = MFMA16(pa0, vb0, o[j], 0, 0, 0);
            o[j] = MFMA16(pa1, vb1, o[j], 0, 0, 0);
        }
    }

    // epilogue: out[b][s][h*64+hd] = O/l  —  FLOAT32 store
#pragma unroll
    for (int j = 0; j < 4; j++)
#pragma unroll
        for (int r = 0; r < 4; r++) {
            int s = qt * 64 + w * 16 + quad * 4 + r;
            out[(size_t)(b * 2048 + s) * 1024 + h * 64 + j * 16 + li] =
                o[j][r] / lrow[r];
        }
}

// ---------------------------------------------------------------------------
extern "C" void kernel_launch(void* const* d_in, const int* in_sizes, int n_in,
                              void* d_out, int out_size, void* d_ws, size_t ws_size,
                              hipStream_t stream)
{
    (void)in_sizes; (void)n_in; (void)out_size; (void)ws_size;
    const float* x   = (const float*)d_in[0];   // (2,2048,1024) f32
    const float* wq  = (const float*)d_in[1];   // (1024,1024)  f32
    const float* wkv = (const float*)d_in[2];   // (2048,1024)  f32
    // d_in[3] = causal mask (int32) — computed analytically in attn

    ushort* raw = (ushort*)d_ws;                  // 4096 x 3072 bf16
    ushort* Qb  = raw + 4096 * 3072;              // (B,H,S,Hd)
    ushort* Kb  = Qb + 2 * 16 * 2048 * 64;        // (B,H,S,Hd)
    ushort* Vt  = Kb + 2 * 16 * 2048 * 64;        // (B,H,Hd,S)
    float* out  = (float*)d_out;                  // FLOAT32 output

    dim3 g1(32, 24);
    gemm_qkv<<<g1, 256, 0, stream>>>(x, wq, wkv, raw);
    rope_qk<<<16384, 256, 0, stream>>>(raw, Qb, Kb);
    dim3 g3(32, 32);
    v_transpose<<<g3, 256, 0, stream>>>(raw, Vt);
    dim3 g4(32, 32);
    attn<<<g4, 256, 0, stream>>>(Qb, Kb, Vt, out);
}

// Round 11
// 265.510 us; speedup vs baseline: 1.2121x; 1.2121x over previous
//
#include <hip/hip_runtime.h>
#include <hip/hip_bf16.h>
#include <math.h>

// ---------------------------------------------------------------------------
// CausalSelfAttention: B=2, S=2048, D=1024, H=16, Hd=64. f32 in / f32 out.
// R11: (1) bf16 pre-convert + global_load_lds(16B) m97-style GEMM;
//      (2) attn 128-row Q-tiles, 32 rows/wave (2x MFMA per barrier).
// ws layout (50 MB, same footprint as passing R10):
//   raw[4096x3072] | Qb (aliases xb pre-rope) | Kb (aliases wb) | Vt
// ---------------------------------------------------------------------------

typedef short bfrag __attribute__((ext_vector_type(8)));   // 8 bf16 = 4 VGPR
typedef float f32x4 __attribute__((ext_vector_type(4)));

__device__ __forceinline__ float bf2f(ushort u) {
    union { uint i; float f; } v; v.i = ((uint)u) << 16; return v.f;
}
__device__ __forceinline__ ushort f2bf(float f) {
    union { uint i; float f; } v; v.f = f;
    uint u = v.i;
    return (ushort)((u + 0x7fffu + ((u >> 16) & 1u)) >> 16);  // RNE
}

#define MFMA16 __builtin_amdgcn_mfma_f32_16x16x32_bf16

// async global->LDS, 16B per lane; lds dest = wave-uniform base + lane*16
__device__ __forceinline__ void gl_lds16(const ushort* g, ushort* l) {
    __builtin_amdgcn_global_load_lds(
        (const __attribute__((address_space(1))) void*)g,
        (__attribute__((address_space(3))) void*)l, 16, 0, 0);
}

// ---------------------------------------------------------------------------
// Kernel 0: f32 -> bf16 convert. xb = bf16(x) [4096x1024];
// wb = bf16([Wq;Wkv]) [3072x1024]. 8 elems/thread.
// ---------------------------------------------------------------------------
__global__ __launch_bounds__(256)
void cvt_bf16(const float* __restrict__ x, const float* __restrict__ wq,
              const float* __restrict__ wkv, ushort* __restrict__ xb,
              ushort* __restrict__ wb)
{
    const size_t NX = 4096u * 1024u, NWQ = 1024u * 1024u;
    size_t i8 = ((size_t)blockIdx.x * 256 + threadIdx.x) * 8;
    const float* src;
    ushort* dst;
    if (i8 < NX) { src = x + i8; dst = xb + i8; }
    else {
        size_t j = i8 - NX;
        dst = wb + j;
        src = (j < NWQ) ? (wq + j) : (wkv + (j - NWQ));
    }
    float4 a = *(const float4*)(src);
    float4 c = *(const float4*)(src + 4);
    ushort u[8];
    u[0] = f2bf(a.x); u[1] = f2bf(a.y); u[2] = f2bf(a.z); u[3] = f2bf(a.w);
    u[4] = f2bf(c.x); u[5] = f2bf(c.y); u[6] = f2bf(c.z); u[7] = f2bf(c.w);
    *(uint4*)dst = *(uint4*)u;
}

// ---------------------------------------------------------------------------
// Kernel 1: raw[m][n] = sum_k xb[m][k] * wb[n][k]. 128x128 tile, BK=32,
// 256 thr, global_load_lds(16B) staging (m97 pattern: unpadded LDS,
// lane-order-contiguous layout).
// ---------------------------------------------------------------------------
__global__ __launch_bounds__(256)
void gemm_qkv(const ushort* __restrict__ xb, const ushort* __restrict__ wb,
              ushort* __restrict__ raw)
{
    __shared__ ushort Ash[128][32];
    __shared__ ushort Bsh[128][32];

    const int tid  = threadIdx.x;
    const int lane = tid & 63, wv = tid >> 6;
    const int wm = wv >> 1, wn = wv & 1;
    const int quad = lane >> 4, li = lane & 15;
    const int m0 = blockIdx.x * 128, n0 = blockIdx.y * 128;

    f32x4 acc[4][4];
#pragma unroll
    for (int i = 0; i < 4; i++)
#pragma unroll
        for (int j = 0; j < 4; j++) acc[i][j] = (f32x4){0.f, 0.f, 0.f, 0.f};

    // staging: wave wv covers rows wv*32 .. wv*32+31 (two 16-row issues);
    // lane l -> row l>>2, kofs (l&3)*8  ==  lds base + l*16 bytes
    const int rsub = lane >> 2, kofs = (lane & 3) * 8;
    const ushort* gA0 = xb + (size_t)(m0 + wv * 32 + rsub) * 1024 + kofs;
    const ushort* gA1 = gA0 + 16 * 1024;
    const ushort* gB0 = wb + (size_t)(n0 + wv * 32 + rsub) * 1024 + kofs;
    const ushort* gB1 = gB0 + 16 * 1024;

    for (int k0 = 0; k0 < 1024; k0 += 32) {
        __syncthreads();   // previous iteration's LDS reads done
        gl_lds16(gA0 + k0, &Ash[wv * 32][0]);
        gl_lds16(gA1 + k0, &Ash[wv * 32 + 16][0]);
        gl_lds16(gB0 + k0, &Bsh[wv * 32][0]);
        gl_lds16(gB1 + k0, &Bsh[wv * 32 + 16][0]);
        __syncthreads();   // drains vmcnt: staged data visible

        bfrag af[4], bf[4];
#pragma unroll
        for (int i = 0; i < 4; i++)
            af[i] = *(const bfrag*)&Ash[wm * 64 + i * 16 + li][quad * 8];
#pragma unroll
        for (int j = 0; j < 4; j++)
            bf[j] = *(const bfrag*)&Bsh[wn * 64 + j * 16 + li][quad * 8];
#pragma unroll
        for (int i = 0; i < 4; i++)
#pragma unroll
            for (int j = 0; j < 4; j++)
                acc[i][j] = MFMA16(af[i], bf[j], acc[i][j], 0, 0, 0);
    }

    // epilogue: C/D layout col=lane&15, row=quad*4+reg (m89-verified)
#pragma unroll
    for (int i = 0; i < 4; i++)
#pragma unroll
        for (int j = 0; j < 4; j++)
#pragma unroll
            for (int r = 0; r < 4; r++) {
                int m = m0 + wm * 64 + i * 16 + quad * 4 + r;
                int n = n0 + wn * 64 + j * 16 + li;
                raw[m * 3072 + n] = f2bf(acc[i][j][r]);
            }
}

// ---------------------------------------------------------------------------
// Kernel 2: RoPE on q,k; scatter to (B,H,S,Hd) bf16. raw row: [0,1024)=q,
// [1024,3072) kv interleave n = 1024 + (h*64+hd)*2 + {0=k,1=v}.
// ---------------------------------------------------------------------------
__global__ __launch_bounds__(256)
void rope_qk(const ushort* __restrict__ raw, ushort* __restrict__ Qb,
             ushort* __restrict__ Kb)
{
    int t  = blockIdx.x * 256 + threadIdx.x;   // 4M threads
    int hd = t & 63;
    int h  = (t >> 6) & 15;
    int s  = (t >> 10) & 2047;
    int b  = t >> 21;
    int m  = b * 2048 + s;
    int fi = hd & 31;
    float invf = (float)exp((double)fi * -0.28782313662425574); // 1e4^(-fi/32)
    float thf  = (float)s * invf;
    const double TWO_PI = 6.283185307179586476925287;
    double th = (double)thf;
    double kq = __builtin_rint(th * (1.0 / TWO_PI));
    float r = (float)(th - kq * TWO_PI);
    float sn = sinf(r), cs = cosf(r);          // reduced: safe under fast-math

    const ushort* rp = raw + m * 3072;
    int odst = ((b * 16 + h) * 2048 + s) * 64 + hd;

    float qv = bf2f(rp[h * 64 + hd]);
    float qp = bf2f(rp[h * 64 + (hd ^ 32)]);
    float qr = (hd < 32) ? -qp : qp;            // rotate_half
    Qb[odst] = f2bf(qv * cs + qr * sn);

    float kv = bf2f(rp[1024 + (h * 64 + hd) * 2]);
    float kp = bf2f(rp[1024 + (h * 64 + (hd ^ 32)) * 2]);
    float kr = (hd < 32) ? -kp : kp;
    Kb[odst] = f2bf(kv * cs + kr * sn);
}

// ---------------------------------------------------------------------------
// Kernel 3: V -> Vt (B,H,Hd,S) bf16, 64x64 tiles via LDS.
// ---------------------------------------------------------------------------
__global__ __launch_bounds__(256)
void v_transpose(const ushort* __restrict__ raw, ushort* __restrict__ Vt)
{
    __shared__ ushort tile[64][65];
    const int bh = blockIdx.y;
    const int st = blockIdx.x;
    const int b = bh >> 4, h = bh & 15;
    const int t = threadIdx.x;

    int sl = t >> 2, c0 = (t & 3) * 16;
    const ushort* rp = raw + (b * 2048 + st * 64 + sl) * 3072
                          + 1024 + (h * 64 + c0) * 2 + 1;
#pragma unroll
    for (int j = 0; j < 16; j++) tile[sl][c0 + j] = rp[2 * j];
    __syncthreads();
    int hd = t >> 2, s0 = (t & 3) * 16;
    ushort* op = Vt + (bh * 64 + hd) * 2048 + st * 64 + s0;
#pragma unroll
    for (int j = 0; j < 16; j++) op[j] = tile[s0 + j][hd];
}

// ---------------------------------------------------------------------------
// Kernel 4: causal flash attention. 1 WG (256 thr) = (b,h) x 128-row Q-tile.
// Wave w owns 32 q rows (two 16-row m-frags). 64-wide K-tiles; online
// softmax; P C-layout -> LDS -> A-layout. F32 output store.
// ---------------------------------------------------------------------------
__global__ __launch_bounds__(256)
void attn(const ushort* __restrict__ Qb, const ushort* __restrict__ Kb,
          const ushort* __restrict__ Vt, float* __restrict__ out)
{
    __shared__ ushort Ksh[64][72];      // [kpos][hd]
    __shared__ ushort Vsh[64][72];      // [hd][kpos]
    __shared__ ushort Psh[4][32][72];   // per-wave P, [qrow32][kpos]

    const int tid  = threadIdx.x;
    const int lane = tid & 63, w = tid >> 6;
    const int quad = lane >> 4, li = lane & 15;
    const int qt = 15 - (int)blockIdx.x;           // heavy tiles first
    const int bh = blockIdx.y;
    const int b = bh >> 4, h = bh & 15;

    bfrag qa[2][2];
#pragma unroll
    for (int mi = 0; mi < 2; mi++) {
        const ushort* qp =
            Qb + (size_t)(bh * 2048 + qt * 128 + w * 32 + mi * 16 + li) * 64;
        qa[mi][0] = *(const bfrag*)(qp + quad * 8);
        qa[mi][1] = *(const bfrag*)(qp + quad * 8 + 32);
    }

    f32x4 o[2][4];
    float mrow[2][4], lrow[2][4];
#pragma unroll
    for (int mi = 0; mi < 2; mi++)
#pragma unroll
        for (int j = 0; j < 4; j++) o[mi][j] = (f32x4){0.f, 0.f, 0.f, 0.f};
#pragma unroll
    for (int mi = 0; mi < 2; mi++)
#pragma unroll
        for (int r = 0; r < 4; r++) { mrow[mi][r] = -3.0e38f; lrow[mi][r] = 0.f; }

    const int srow = tid >> 2, sc0 = (tid & 3) * 16;
    const ushort* kbase = Kb + (size_t)bh * 2048 * 64;
    const ushort* vbase = Vt + (size_t)bh * 64 * 2048;
    int qg0[2];
#pragma unroll
    for (int mi = 0; mi < 2; mi++)
        qg0[mi] = qt * 128 + w * 32 + mi * 16 + quad * 4;

    const int ktmax = 2 * qt + 1;
    for (int kt = 0; kt <= ktmax; ++kt) {
        __syncthreads();
        {
            const ushort* gk = kbase + (kt * 64 + srow) * 64 + sc0;
            *(uint4*)&Ksh[srow][sc0]     = *(const uint4*)gk;
            *(uint4*)&Ksh[srow][sc0 + 8] = *(const uint4*)(gk + 8);
            const ushort* gv = vbase + srow * 2048 + kt * 64 + sc0;
            *(uint4*)&Vsh[srow][sc0]     = *(const uint4*)gv;
            *(uint4*)&Vsh[srow][sc0 + 8] = *(const uint4*)(gv + 8);
        }
        __syncthreads();

        bfrag kb0[4], kb1[4];
#pragma unroll
        for (int j = 0; j < 4; j++) {
            kb0[j] = *(const bfrag*)&Ksh[j * 16 + li][quad * 8];
            kb1[j] = *(const bfrag*)&Ksh[j * 16 + li][quad * 8 + 32];
        }

        f32x4 sc[2][4];
#pragma unroll
        for (int mi = 0; mi < 2; mi++)
#pragma unroll
            for (int j = 0; j < 4; j++) {
                f32x4 z = (f32x4){0.f, 0.f, 0.f, 0.f};
                z = MFMA16(qa[mi][0], kb0[j], z, 0, 0, 0);
                z = MFMA16(qa[mi][1], kb1[j], z, 0, 0, 0);
                sc[mi][j] = z;
            }

        float mloc[2][4];
#pragma unroll
        for (int mi = 0; mi < 2; mi++)
#pragma unroll
            for (int r = 0; r < 4; r++) mloc[mi][r] = -3.0e38f;
#pragma unroll
        for (int j = 0; j < 4; j++) {
            int kg = kt * 64 + j * 16 + li;
#pragma unroll
            for (int mi = 0; mi < 2; mi++)
#pragma unroll
                for (int r = 0; r < 4; r++) {
                    float v = sc[mi][j][r] * 0.125f;
                    v = (kg <= qg0[mi] + r) ? v : -3.0e38f;
                    sc[mi][j][r] = v;
                    mloc[mi][r] = fmaxf(mloc[mi][r], v);
                }
        }
#pragma unroll
        for (int off = 1; off < 16; off <<= 1)
#pragma unroll
            for (int mi = 0; mi < 2; mi++)
#pragma unroll
                for (int r = 0; r < 4; r++)
                    mloc[mi][r] = fmaxf(mloc[mi][r], __shfl_xor(mloc[mi][r], off));

        float alpha[2][4], mnew[2][4], rsum[2][4];
#pragma unroll
        for (int mi = 0; mi < 2; mi++)
#pragma unroll
            for (int r = 0; r < 4; r++) {
                mnew[mi][r]  = fmaxf(mrow[mi][r], mloc[mi][r]);
                alpha[mi][r] = __expf(mrow[mi][r] - mnew[mi][r]);
                mrow[mi][r]  = mnew[mi][r];
                rsum[mi][r]  = 0.f;
            }
#pragma unroll
        for (int mi = 0; mi < 2; mi++)
#pragma unroll
            for (int j = 0; j < 4; j++)
#pragma unroll
                for (int r = 0; r < 4; r++) {
                    float pv = __expf(sc[mi][j][r] - mnew[mi][r]);
                    sc[mi][j][r] = pv;
                    rsum[mi][r] += pv;
                }
#pragma unroll
        for (int off = 1; off < 16; off <<= 1)
#pragma unroll
            for (int mi = 0; mi < 2; mi++)
#pragma unroll
                for (int r = 0; r < 4; r++)
                    rsum[mi][r] += __shfl_xor(rsum[mi][r], off);
#pragma unroll
        for (int mi = 0; mi < 2; mi++)
#pragma unroll
            for (int r = 0; r < 4; r++)
                lrow[mi][r] = lrow[mi][r] * alpha[mi][r] + rsum[mi][r];
#pragma unroll
        for (int mi = 0; mi < 2; mi++)
#pragma unroll
            for (int j = 0; j < 4; j++)
#pragma unroll
                for (int r = 0; r < 4; r++) o[mi][j][r] *= alpha[mi][r];

        // P: C-layout -> LDS -> A-layout
#pragma unroll
        for (int mi = 0; mi < 2; mi++)
#pragma unroll
            for (int j = 0; j < 4; j++)
#pragma unroll
                for (int r = 0; r < 4; r++)
                    Psh[w][mi * 16 + quad * 4 + r][j * 16 + li] =
                        f2bf(sc[mi][j][r]);
        asm volatile("" ::: "memory");
        __syncthreads();
        bfrag pa0[2], pa1[2];
#pragma unroll
        for (int mi = 0; mi < 2; mi++) {
            pa0[mi] = *(const bfrag*)&Psh[w][mi * 16 + li][quad * 8];
            pa1[mi] = *(const bfrag*)&Psh[w][mi * 16 + li][quad * 8 + 32];
        }

#pragma unroll
        for (int j = 0; j < 4; j++) {
            bfrag vb0 = *(const bfrag*)&Vsh[j * 16 + li][quad * 8];
            bfrag vb1 = *(const bfrag*)&Vsh[j * 16 + li][quad * 8 + 32];
#pragma unroll
            for (int mi = 0; mi < 2; mi++) {
                o[mi][j] = MFMA16(pa0[mi], vb0, o[mi][j], 0, 0, 0);
                o[mi][j] = MFMA16(pa1[mi], vb1, o[mi][j], 0, 0, 0);
            }
        }
    }

    // epilogue: out[b][s][h*64+hd] = O/l  — FLOAT32 store
#pragma unroll
    for (int mi = 0; mi < 2; mi++)
#pragma unroll
        for (int j = 0; j < 4; j++)
#pragma unroll
            for (int r = 0; r < 4; r++) {
                int s = qt * 128 + w * 32 + mi * 16 + quad * 4 + r;
                out[(size_t)(b * 2048 + s) * 1024 + h * 64 + j * 16 + li] =
                    o[mi][j][r] / lrow[mi][r];
            }
}

// ---------------------------------------------------------------------------
extern "C" void kernel_launch(void* const* d_in, const int* in_sizes, int n_in,
                              void* d_out, int out_size, void* d_ws, size_t ws_size,
                              hipStream_t stream)
{
    (void)in_sizes; (void)n_in; (void)out_size; (void)ws_size;
    const float* x   = (const float*)d_in[0];   // (2,2048,1024) f32
    const float* wq  = (const float*)d_in[1];   // (1024,1024)  f32
    const float* wkv = (const float*)d_in[2];   // (2048,1024)  f32
    // d_in[3] = causal mask — computed analytically in attn

    ushort* raw = (ushort*)d_ws;                  // 4096 x 3072 bf16
    ushort* Qb  = raw + (size_t)4096 * 3072;      // (B,H,S,Hd) — aliases xb
    ushort* Kb  = Qb + (size_t)2 * 16 * 2048 * 64;   // aliases wb
    ushort* Vt  = Kb + (size_t)2 * 16 * 2048 * 64;
    ushort* xb  = Qb;                             // bf16 x   (consumed by gemm)
    ushort* wb  = Kb;                             // bf16 W   (consumed by gemm)
    float* out  = (float*)d_out;                  // FLOAT32 output

    cvt_bf16<<<3584, 256, 0, stream>>>(x, wq, wkv, xb, wb);
    dim3 g1(32, 24);
    gemm_qkv<<<g1, 256, 0, stream>>>(xb, wb, raw);
    rope_qk<<<16384, 256, 0, stream>>>(raw, Qb, Kb);
    dim3 g3(32, 32);
    v_transpose<<<g3, 256, 0, stream>>>(raw, Vt);
    dim3 g4(16, 32);
    attn<<<g4, 256, 0, stream>>>(Qb, Kb, Vt, out);
}

// Round 13
// 246.037 us; speedup vs baseline: 1.3080x; 1.0791x over previous
//
#include <hip/hip_runtime.h>
#include <hip/hip_bf16.h>
#include <math.h>

// ---------------------------------------------------------------------------
// CausalSelfAttention: B=2, S=2048, D=1024, H=16, Hd=64. f32 in / f32 out.
// R12 (R13 resubmit — R12 was a broker/container infra failure):
//      (1) GEMM epilogue fuses RoPE (in-register pair via acc[2][8] shape)
//      + V-transpose; raw buffer eliminated. cos/sin from f32 table.
//      (2) attn: back to 64-row Q-tiles (1024 blocks) + register
//      double-buffer prefetch of K/V + wave-local P sync (lgkmcnt).
// ws: xb | wb | tab | Qb | Kb | Vt  (~40 MB)
// ---------------------------------------------------------------------------

typedef short bfrag __attribute__((ext_vector_type(8)));   // 8 bf16 = 4 VGPR
typedef float f32x4 __attribute__((ext_vector_type(4)));

__device__ __forceinline__ float bf2f(ushort u) {
    union { uint i; float f; } v; v.i = ((uint)u) << 16; return v.f;
}
__device__ __forceinline__ ushort f2bf(float f) {
    union { uint i; float f; } v; v.f = f;
    uint u = v.i;
    return (ushort)((u + 0x7fffu + ((u >> 16) & 1u)) >> 16);  // RNE
}

#define MFMA16 __builtin_amdgcn_mfma_f32_16x16x32_bf16

__device__ __forceinline__ void gl_lds16(const ushort* g, ushort* l) {
    __builtin_amdgcn_global_load_lds(
        (const __attribute__((address_space(1))) void*)g,
        (__attribute__((address_space(3))) void*)l, 16, 0, 0);
}

// ---------------------------------------------------------------------------
// Kernel 0a: f32 -> bf16 convert (xb = x; wb = [Wq;Wkv]).
// ---------------------------------------------------------------------------
__global__ __launch_bounds__(256)
void cvt_bf16(const float* __restrict__ x, const float* __restrict__ wq,
              const float* __restrict__ wkv, ushort* __restrict__ xb,
              ushort* __restrict__ wb)
{
    const size_t NX = 4096u * 1024u, NWQ = 1024u * 1024u;
    size_t i8 = ((size_t)blockIdx.x * 256 + threadIdx.x) * 8;
    const float* src;
    ushort* dst;
    if (i8 < NX) { src = x + i8; dst = xb + i8; }
    else {
        size_t j = i8 - NX;
        dst = wb + j;
        src = (j < NWQ) ? (wq + j) : (wkv + (j - NWQ));
    }
    float4 a = *(const float4*)(src);
    float4 c = *(const float4*)(src + 4);
    ushort u[8];
    u[0] = f2bf(a.x); u[1] = f2bf(a.y); u[2] = f2bf(a.z); u[3] = f2bf(a.w);
    u[4] = f2bf(c.x); u[5] = f2bf(c.y); u[6] = f2bf(c.z); u[7] = f2bf(c.w);
    *(uint4*)dst = *(uint4*)u;
}

// ---------------------------------------------------------------------------
// Kernel 0b: rope table tab[s][fi] = (cos, sin)(s * 10000^(-fi/32)).
// f32 angle (as reference), double range reduction (fast-math-proof).
// ---------------------------------------------------------------------------
__global__ __launch_bounds__(256)
void rope_table(float2* __restrict__ tab)
{
    int t  = blockIdx.x * 256 + threadIdx.x;   // 65536
    int fi = t & 31, s = t >> 5;
    float invf = (float)exp((double)fi * -0.28782313662425574);
    float thf  = (float)s * invf;
    const double TWO_PI = 6.283185307179586476925287;
    double th = (double)thf;
    double kq = __builtin_rint(th * (1.0 / TWO_PI));
    float r = (float)(th - kq * TWO_PI);
    tab[t] = make_float2(cosf(r), sinf(r));
}

// ---------------------------------------------------------------------------
// Kernel 1: QKV GEMM, 128x128 tile, BK=32, global_load_lds(16B) staging.
// Wave wv owns rows wv*32..+31 (acc[2][8]: mi x j over full 128 cols) so the
// RoPE pair (hd^32) is in-lane: q -> acc[mi][j^2][r], k -> acc[mi][j^4][r].
// Epilogue: q-blocks -> rope -> Qb(B,H,S,Hd); kv-blocks: even li lanes =
// k -> rope -> Kb; odd li lanes = v -> Vt(B,H,Hd,S) (8B stores).
// ---------------------------------------------------------------------------
__global__ __launch_bounds__(256)
void gemm_qkv(const ushort* __restrict__ xb, const ushort* __restrict__ wb,
              const float2* __restrict__ tab, ushort* __restrict__ Qb,
              ushort* __restrict__ Kb, ushort* __restrict__ Vt)
{
    __shared__ ushort Ash[128][32];
    __shared__ ushort Bsh[128][32];

    const int tid  = threadIdx.x;
    const int lane = tid & 63, wv = tid >> 6;
    const int quad = lane >> 4, li = lane & 15;
    const int m0 = blockIdx.x * 128, n0 = blockIdx.y * 128;

    f32x4 acc[2][8];
#pragma unroll
    for (int mi = 0; mi < 2; mi++)
#pragma unroll
        for (int j = 0; j < 8; j++) acc[mi][j] = (f32x4){0.f, 0.f, 0.f, 0.f};

    const int rsub = lane >> 2, kofs = (lane & 3) * 8;
    const ushort* gA0 = xb + (size_t)(m0 + wv * 32 + rsub) * 1024 + kofs;
    const ushort* gA1 = gA0 + 16 * 1024;
    const ushort* gB0 = wb + (size_t)(n0 + wv * 32 + rsub) * 1024 + kofs;
    const ushort* gB1 = gB0 + 16 * 1024;

    for (int k0 = 0; k0 < 1024; k0 += 32) {
        __syncthreads();
        gl_lds16(gA0 + k0, &Ash[wv * 32][0]);
        gl_lds16(gA1 + k0, &Ash[wv * 32 + 16][0]);
        gl_lds16(gB0 + k0, &Bsh[wv * 32][0]);
        gl_lds16(gB1 + k0, &Bsh[wv * 32 + 16][0]);
        __syncthreads();

        bfrag af[2], bf[8];
#pragma unroll
        for (int mi = 0; mi < 2; mi++)
            af[mi] = *(const bfrag*)&Ash[wv * 32 + mi * 16 + li][quad * 8];
#pragma unroll
        for (int j = 0; j < 8; j++)
            bf[j] = *(const bfrag*)&Bsh[j * 16 + li][quad * 8];
#pragma unroll
        for (int mi = 0; mi < 2; mi++)
#pragma unroll
            for (int j = 0; j < 8; j++)
                acc[mi][j] = MFMA16(af[mi], bf[j], acc[mi][j], 0, 0, 0);
    }

    // ---- fused epilogue (C/D: row = quad*4+r + mi*16 + wv*32, col = j*16+li)
    if (n0 < 1024) {
        // q region: head = n0/64 + (j>>2), hd = (j&3)*16 + li, fi = hd&31
        const int hbase = n0 >> 6;
#pragma unroll
        for (int mi = 0; mi < 2; mi++)
#pragma unroll
            for (int r = 0; r < 4; r++) {
                int m = m0 + wv * 32 + mi * 16 + quad * 4 + r;
                int bb = m >> 11, s = m & 2047;
                float2 t0 = tab[s * 32 + li];        // fi = li
                float2 t1 = tab[s * 32 + li + 16];   // fi = li+16
#pragma unroll
                for (int j = 0; j < 8; j++) {
                    float v  = acc[mi][j][r];
                    float vp = acc[mi][j ^ 2][r];    // hd^32 partner
                    float2 tt = (j & 1) ? t1 : t0;
                    float rh = (j & 2) ? vp : -vp;   // hd<32 -> -x[hd+32]
                    int h = hbase + (j >> 2), hd = (j & 3) * 16 + li;
                    Qb[(size_t)((bb * 16 + h) * 2048 + s) * 64 + hd] =
                        f2bf(v * tt.x + rh * tt.y);
                }
            }
    } else {
        const int h = (n0 - 1024) >> 7;
        const int li2 = li >> 1;
        if ((li & 1) == 0) {
            // k lanes: hd = j*8 + li2, fi = (j&3)*8 + li2
#pragma unroll
            for (int mi = 0; mi < 2; mi++)
#pragma unroll
                for (int r = 0; r < 4; r++) {
                    int m = m0 + wv * 32 + mi * 16 + quad * 4 + r;
                    int bb = m >> 11, s = m & 2047;
                    float2 tt4[4];
#pragma unroll
                    for (int jj = 0; jj < 4; jj++)
                        tt4[jj] = tab[s * 32 + jj * 8 + li2];
#pragma unroll
                    for (int j = 0; j < 8; j++) {
                        float v  = acc[mi][j][r];
                        float vp = acc[mi][j ^ 4][r];   // hd^32 partner
                        float2 tt = tt4[j & 3];
                        float rh = (j & 4) ? vp : -vp;  // hd<32 -> -x[hd+32]
                        int hd = j * 8 + li2;
                        Kb[(size_t)((bb * 16 + h) * 2048 + s) * 64 + hd] =
                            f2bf(v * tt.x + rh * tt.y);
                    }
                }
        } else {
            // v lanes: hd = j*8 + li2; Vt[(bh*64+hd)][s], 4 consecutive s
#pragma unroll
            for (int mi = 0; mi < 2; mi++) {
                int m4 = m0 + wv * 32 + mi * 16 + quad * 4;
                int bb = m4 >> 11, s0 = m4 & 2047;
#pragma unroll
                for (int j = 0; j < 8; j++) {
                    int hd = j * 8 + li2;
                    ushort u4[4];
#pragma unroll
                    for (int r = 0; r < 4; r++) u4[r] = f2bf(acc[mi][j][r]);
                    *(ushort4*)&Vt[(size_t)((bb * 16 + h) * 64 + hd) * 2048 + s0] =
                        *(ushort4*)u4;
                }
            }
        }
    }
}

// ---------------------------------------------------------------------------
// Kernel 2: causal flash attention. 1 WG (256 thr) = (b,h) x 64-row Q-tile
// (R10-validated shape), + register double-buffer K/V prefetch, + wave-local
// P sync. F32 output store.
// ---------------------------------------------------------------------------
__global__ __launch_bounds__(256)
void attn(const ushort* __restrict__ Qb, const ushort* __restrict__ Kb,
          const ushort* __restrict__ Vt, float* __restrict__ out)
{
    __shared__ ushort Ksh[64][72];
    __shared__ ushort Vsh[64][72];
    __shared__ ushort Psh[4][16][72];

    const int tid  = threadIdx.x;
    const int lane = tid & 63, w = tid >> 6;
    const int quad = lane >> 4, li = lane & 15;
    const int qt = 31 - (int)blockIdx.x;           // heavy tiles first
    const int bh = blockIdx.y;
    const int b = bh >> 4, h = bh & 15;

    const int qrow = qt * 64 + w * 16 + li;
    const ushort* qp = Qb + (size_t)(bh * 2048 + qrow) * 64;
    bfrag qa0 = *(const bfrag*)(qp + quad * 8);
    bfrag qa1 = *(const bfrag*)(qp + quad * 8 + 32);

    f32x4 o[4];
#pragma unroll
    for (int j = 0; j < 4; j++) o[j] = (f32x4){0.f, 0.f, 0.f, 0.f};
    float mrow[4], lrow[4];
#pragma unroll
    for (int r = 0; r < 4; r++) { mrow[r] = -3.0e38f; lrow[r] = 0.f; }

    const int srow = tid >> 2, sc0 = (tid & 3) * 16;
    const ushort* kbase = Kb + (size_t)bh * 2048 * 64;
    const ushort* vbase = Vt + (size_t)bh * 64 * 2048;
    const int qg0 = qt * 64 + w * 16 + quad * 4;

    // preload kt=0 into registers
    uint4 ka, kb_, va, vb_;
    {
        const ushort* gk = kbase + (size_t)srow * 64 + sc0;
        ka  = *(const uint4*)gk;
        kb_ = *(const uint4*)(gk + 8);
        const ushort* gv = vbase + (size_t)srow * 2048 + sc0;
        va  = *(const uint4*)gv;
        vb_ = *(const uint4*)(gv + 8);
    }

    for (int kt = 0; kt <= qt; ++kt) {
        __syncthreads();   // previous iteration's LDS readers done
        *(uint4*)&Ksh[srow][sc0]     = ka;
        *(uint4*)&Ksh[srow][sc0 + 8] = kb_;
        *(uint4*)&Vsh[srow][sc0]     = va;
        *(uint4*)&Vsh[srow][sc0 + 8] = vb_;
        __syncthreads();   // staged data visible

        if (kt < qt) {     // prefetch next tile; latency hidden by compute
            const ushort* gk = kbase + (size_t)((kt + 1) * 64 + srow) * 64 + sc0;
            ka  = *(const uint4*)gk;
            kb_ = *(const uint4*)(gk + 8);
            const ushort* gv = vbase + (size_t)srow * 2048 + (kt + 1) * 64 + sc0;
            va  = *(const uint4*)gv;
            vb_ = *(const uint4*)(gv + 8);
        }

        f32x4 sc[4];
#pragma unroll
        for (int j = 0; j < 4; j++) {
            bfrag kb0 = *(const bfrag*)&Ksh[j * 16 + li][quad * 8];
            bfrag kb1 = *(const bfrag*)&Ksh[j * 16 + li][quad * 8 + 32];
            f32x4 z = (f32x4){0.f, 0.f, 0.f, 0.f};
            z = MFMA16(qa0, kb0, z, 0, 0, 0);
            z = MFMA16(qa1, kb1, z, 0, 0, 0);
            sc[j] = z;
        }

        float mloc[4];
#pragma unroll
        for (int r = 0; r < 4; r++) mloc[r] = -3.0e38f;
#pragma unroll
        for (int j = 0; j < 4; j++) {
            int kg = kt * 64 + j * 16 + li;
#pragma unroll
            for (int r = 0; r < 4; r++) {
                float v = sc[j][r] * 0.125f;
                v = (kg <= qg0 + r) ? v : -3.0e38f;
                sc[j][r] = v;
                mloc[r] = fmaxf(mloc[r], v);
            }
        }
#pragma unroll
        for (int off = 1; off < 16; off <<= 1)
#pragma unroll
            for (int r = 0; r < 4; r++)
                mloc[r] = fmaxf(mloc[r], __shfl_xor(mloc[r], off));

        float alpha[4], mnew[4], rsum[4];
#pragma unroll
        for (int r = 0; r < 4; r++) {
            mnew[r]  = fmaxf(mrow[r], mloc[r]);
            alpha[r] = __expf(mrow[r] - mnew[r]);
            mrow[r]  = mnew[r];
            rsum[r]  = 0.f;
        }
#pragma unroll
        for (int j = 0; j < 4; j++)
#pragma unroll
            for (int r = 0; r < 4; r++) {
                float pv = __expf(sc[j][r] - mnew[r]);
                sc[j][r] = pv;
                rsum[r] += pv;
            }
#pragma unroll
        for (int off = 1; off < 16; off <<= 1)
#pragma unroll
            for (int r = 0; r < 4; r++)
                rsum[r] += __shfl_xor(rsum[r], off);
#pragma unroll
        for (int r = 0; r < 4; r++) lrow[r] = lrow[r] * alpha[r] + rsum[r];
#pragma unroll
        for (int j = 0; j < 4; j++)
#pragma unroll
            for (int r = 0; r < 4; r++) o[j][r] *= alpha[r];

        // P: C-layout -> LDS -> A-layout (Psh[w] is wave-private: wave-local
        // sync suffices; ds ops of one wave complete under lgkmcnt(0))
#pragma unroll
        for (int j = 0; j < 4; j++)
#pragma unroll
            for (int r = 0; r < 4; r++)
                Psh[w][quad * 4 + r][j * 16 + li] = f2bf(sc[j][r]);
        asm volatile("s_waitcnt lgkmcnt(0)" ::: "memory");
        bfrag pa0 = *(const bfrag*)&Psh[w][li][quad * 8];
        bfrag pa1 = *(const bfrag*)&Psh[w][li][quad * 8 + 32];

#pragma unroll
        for (int j = 0; j < 4; j++) {
            bfrag vb0 = *(const bfrag*)&Vsh[j * 16 + li][quad * 8];
            bfrag vb1 = *(const bfrag*)&Vsh[j * 16 + li][quad * 8 + 32];
            o[j] = MFMA16(pa0, vb0, o[j], 0, 0, 0);
            o[j] = MFMA16(pa1, vb1, o[j], 0, 0, 0);
        }
    }

    // epilogue: out[b][s][h*64+hd] = O/l  — FLOAT32 store
#pragma unroll
    for (int j = 0; j < 4; j++)
#pragma unroll
        for (int r = 0; r < 4; r++) {
            int s = qt * 64 + w * 16 + quad * 4 + r;
            out[(size_t)(b * 2048 + s) * 1024 + h * 64 + j * 16 + li] =
                o[j][r] / lrow[r];
        }
}

// ---------------------------------------------------------------------------
extern "C" void kernel_launch(void* const* d_in, const int* in_sizes, int n_in,
                              void* d_out, int out_size, void* d_ws, size_t ws_size,
                              hipStream_t stream)
{
    (void)in_sizes; (void)n_in; (void)out_size; (void)ws_size;
    const float* x   = (const float*)d_in[0];   // (2,2048,1024) f32
    const float* wq  = (const float*)d_in[1];   // (1024,1024)  f32
    const float* wkv = (const float*)d_in[2];   // (2048,1024)  f32
    // d_in[3] = causal mask — computed analytically

    ushort* xb = (ushort*)d_ws;                       // 4096x1024 bf16
    ushort* wb = xb + (size_t)4096 * 1024;            // 3072x1024 bf16
    float2* tab = (float2*)(wb + (size_t)3072 * 1024); // 2048x32 (cos,sin)
    ushort* Qb = (ushort*)(tab + 65536);              // (B,H,S,Hd)
    ushort* Kb = Qb + (size_t)2 * 16 * 2048 * 64;     // (B,H,S,Hd)
    ushort* Vt = Kb + (size_t)2 * 16 * 2048 * 64;     // (B,H,Hd,S)
    float* out = (float*)d_out;                       // f32 output

    cvt_bf16<<<3584, 256, 0, stream>>>(x, wq, wkv, xb, wb);
    rope_table<<<256, 256, 0, stream>>>(tab);
    dim3 g1(32, 24);
    gemm_qkv<<<g1, 256, 0, stream>>>(xb, wb, tab, Qb, Kb, Vt);
    dim3 g4(32, 32);
    attn<<<g4, 256, 0, stream>>>(Qb, Kb, Vt, out);
}